// Round 12
// baseline (169.394 us; speedup 1.0000x reference)
//
#include <hip/hip_runtime.h>

// LPSC cell. c == 0.0 => g-branch dead: new_S = Y + (-Y + k1*x1 - k2*x2).
// Ladder: 52.8 (R3) -> ~41 (R7) -> ~38-40 (R8/R10/R11). Four null levers
// (instr count, packing, occupancy bounds, NT stores) => floor is per-wave
// exposed VMEM latency: load -> long dependent chain -> store, ~2 waves/SIMD
// achieved. R12: persistent grid (2048 wg = 8/CU), 4 rows/thread strided by
// grid, REGISTER DOUBLE-BUFFER: issue next row's loads before computing the
// current row -> compute covers VMEM latency via ILP, independent of occupancy.

#define LDIM 5
#define HDIM 16
constexpr int BLOCK = 256;
constexpr int GRID  = 2048;  // 8 wg/CU nominal

typedef float f32x2 __attribute__((ext_vector_type(2)));

__device__ __forceinline__ f32x2 fma2(f32x2 a, f32x2 b, f32x2 c) {
    return __builtin_elementwise_fma(a, b, c);
}
__device__ __forceinline__ f32x2 max2(f32x2 a, f32x2 b) {
    return __builtin_elementwise_max(a, b);
}

struct RowIn {
    f32x2 xv;
    float y;
    float z0, z1, z2, z3, z4;
};

__device__ __forceinline__ void load_row(const float* __restrict__ inputs,
                                         const float* __restrict__ Zin,
                                         const float* __restrict__ Yin,
                                         unsigned row, RowIn& R) {
    R.xv = reinterpret_cast<const f32x2*>(inputs)[row];
    R.y  = Yin[row];
    const float* zr = Zin + (size_t)row * LDIM;
    R.z0 = zr[0]; R.z1 = zr[1]; R.z2 = zr[2]; R.z3 = zr[3]; R.z4 = zr[4];
}

__device__ __forceinline__ void compute_store(
    const RowIn& R, unsigned row,
    const float* __restrict__ A,
    const f32x2* __restrict__ W1, const f32x2* __restrict__ B1,
    const f32x2* __restrict__ W2, const f32x2* __restrict__ B2,
    const f32x2* __restrict__ W3, f32x2 b3,
    float* __restrict__ out, unsigned B)
{
    float z[LDIM] = {R.z0, R.z1, R.z2, R.z3, R.z4};

    // new_Z = Z @ A (5x5 scalar)
    float nz[LDIM];
    #pragma unroll
    for (int j = 0; j < LDIM; ++j) nz[j] = 0.0f;
    #pragma unroll
    for (int k = 0; k < LDIM; ++k)
        #pragma unroll
        for (int j = 0; j < LDIM; ++j)
            nz[j] = fmaf(z[k], A[k * LDIM + j], nz[j]);

    // h = relu(nz @ w2a + b2a), j packed
    f32x2 h[HDIM / 2];
    #pragma unroll
    for (int jp = 0; jp < HDIM / 2; ++jp) h[jp] = B1[jp];
    #pragma unroll
    for (int k = 0; k < LDIM; ++k) {
        const f32x2 a2 = {nz[k], nz[k]};
        #pragma unroll
        for (int jp = 0; jp < HDIM / 2; ++jp)
            h[jp] = fma2(a2, W1[k * (HDIM / 2) + jp], h[jp]);
    }
    const f32x2 zero = {0.0f, 0.0f};
    #pragma unroll
    for (int jp = 0; jp < HDIM / 2; ++jp) h[jp] = max2(h[jp], zero);

    // g2 = relu(h @ w2b + b2b), j packed
    f32x2 g2[HDIM / 2];
    #pragma unroll
    for (int jp = 0; jp < HDIM / 2; ++jp) g2[jp] = B2[jp];
    #pragma unroll
    for (int k = 0; k < HDIM; ++k) {
        const float hk = (k & 1) ? h[k >> 1].y : h[k >> 1].x;  // static index
        const f32x2 a2 = {hk, hk};
        #pragma unroll
        for (int jp = 0; jp < HDIM / 2; ++jp)
            g2[jp] = fma2(a2, W2[k * (HDIM / 2) + jp], g2[jp]);
    }
    #pragma unroll
    for (int jp = 0; jp < HDIM / 2; ++jp) g2[jp] = max2(g2[jp], zero);

    // {k1,k2} = g2 @ w2c + b2c
    f32x2 k12 = b3;
    #pragma unroll
    for (int k = 0; k < HDIM; ++k) {
        const float gk = (k & 1) ? g2[k >> 1].y : g2[k >> 1].x;
        const f32x2 a2 = {gk, gk};
        k12 = fma2(a2, W3[k], k12);
    }

    const float K1 = fabsf(k12.x);
    const float K2 = fabsf(k12.y);
    // DY = -Y + k1*x1 - k2*x2 (+ 0*g); new_S = Y + DY (reference op order)
    const float ns = R.y + (-R.y + K1 * R.xv.x - K2 * R.xv.y);

    out[row] = ns;
    out[(size_t)6 * B + row] = ns;
    float* oz = out + (size_t)B + (size_t)row * LDIM;
    oz[0] = nz[0]; oz[1] = nz[1]; oz[2] = nz[2]; oz[3] = nz[3]; oz[4] = nz[4];
}

__global__ __launch_bounds__(BLOCK) void lpsc_main(
    const float* __restrict__ inputs,  // (B,2)
    const float* __restrict__ Zin,     // (B,5)
    const float* __restrict__ Yin,     // (B,1)
    const float* __restrict__ A,       // (5,5)
    const float* __restrict__ w2a, const float* __restrict__ b2a,
    const float* __restrict__ w2b, const float* __restrict__ b2b,
    const float* __restrict__ w2c, const float* __restrict__ b2c,
    float* __restrict__ out,           // [B: newS][5B: newZ][B: newS]
    unsigned B)
{
    const f32x2* W1 = reinterpret_cast<const f32x2*>(w2a);  // (5, 8) pairs
    const f32x2* B1 = reinterpret_cast<const f32x2*>(b2a);
    const f32x2* W2 = reinterpret_cast<const f32x2*>(w2b);  // (16, 8) pairs
    const f32x2* B2 = reinterpret_cast<const f32x2*>(b2b);
    const f32x2* W3 = reinterpret_cast<const f32x2*>(w2c);  // 16 pairs {w0,w1}
    const f32x2  b3 = *reinterpret_cast<const f32x2*>(b2c);

    const unsigned S = (unsigned)GRID * BLOCK;               // row stride per sweep
    unsigned ra = blockIdx.x * (unsigned)BLOCK + threadIdx.x;
    if (ra >= B) return;

    RowIn RA, RB;
    load_row(inputs, Zin, Yin, ra, RA);
    unsigned rb = ra + S;

    for (;;) {
        // software pipeline: issue next row's loads, then compute current
        if (rb < B) load_row(inputs, Zin, Yin, rb, RB);
        compute_store(RA, ra, A, W1, B1, W2, B2, W3, b3, out, B);
        if (rb >= B) return;

        ra = rb + S;
        if (ra < B) load_row(inputs, Zin, Yin, ra, RA);
        compute_store(RB, rb, A, W1, B1, W2, B2, W3, b3, out, B);
        if (ra >= B) return;
        rb = ra + S;
    }
}

extern "C" void kernel_launch(void* const* d_in, const int* in_sizes, int n_in,
                              void* d_out, int out_size, void* d_ws, size_t ws_size,
                              hipStream_t stream) {
    const float* inputs = (const float*)d_in[0];
    const float* Zin    = (const float*)d_in[1];
    const float* Yin    = (const float*)d_in[2];
    const float* A      = (const float*)d_in[3];
    const float* w2a    = (const float*)d_in[4];
    const float* b2a    = (const float*)d_in[5];
    const float* w2b    = (const float*)d_in[6];
    const float* b2b    = (const float*)d_in[7];
    const float* w2c    = (const float*)d_in[8];
    const float* b2c    = (const float*)d_in[9];

    const unsigned B = (unsigned)in_sizes[2];  // Y has B elements
    // Persistent-style: fixed grid; each thread sweeps rows strided by GRID*BLOCK.
    // If B is small, shrink grid so every block has work.
    unsigned grid = GRID;
    const unsigned needed = (B + BLOCK - 1) / BLOCK;
    if (needed < grid) grid = needed;

    lpsc_main<<<grid, BLOCK, 0, stream>>>(inputs, Zin, Yin, A, w2a, b2a,
                                          w2b, b2b, w2c, b2c,
                                          (float*)d_out, B);
}

// Round 15
// 144.591 us; speedup vs baseline: 1.1715x; 1.1715x over previous
//
#include <hip/hip_runtime.h>

// LPSC cell. c == 0.0 => g-branch dead: new_S = Y + (-Y + k1*x1 - k2*x2).
// Ladder: 52.8 (R3) -> ~41 (R7) -> ~38 (R8-R11) -> 60 (R12 persistent, REGRESSED).
// R12 lesson: straight-line short-wave kernels win; loops inflate dynamic VALU
// (63% busy at 60us) and long per-wave chains lose. R going 4->2->1 monotonically
// helped => turnover/launch-granularity regime. R13 single variable vs R11:
// BLOCK 256 -> 1024 (8192 -> 2048 workgroups, 16 waves each). If dispatch-rate
// was the floor, expect ~38 -> ~25us. Math/packing/stores identical to R11.
// (R13/R14 benches were broker timeouts — resubmitting unchanged.)

#define LDIM 5
#define HDIM 16
constexpr int BLOCK = 1024;

typedef float f32x2 __attribute__((ext_vector_type(2)));

__device__ __forceinline__ f32x2 fma2(f32x2 a, f32x2 b, f32x2 c) {
    return __builtin_elementwise_fma(a, b, c);
}
__device__ __forceinline__ f32x2 max2(f32x2 a, f32x2 b) {
    return __builtin_elementwise_max(a, b);
}

__global__ __launch_bounds__(BLOCK) void lpsc_main(
    const float* __restrict__ inputs,  // (B,2)
    const float* __restrict__ Zin,     // (B,5)
    const float* __restrict__ Yin,     // (B,1)
    const float* __restrict__ A,       // (5,5)
    const float* __restrict__ w2a, const float* __restrict__ b2a,
    const float* __restrict__ w2b, const float* __restrict__ b2b,
    const float* __restrict__ w2c, const float* __restrict__ b2c,
    float* __restrict__ out,           // [B: newS][5B: newZ][B: newS]
    unsigned B)
{
    const unsigned row = blockIdx.x * (unsigned)BLOCK + threadIdx.x;
    if (row >= B) return;

    const f32x2* W1 = reinterpret_cast<const f32x2*>(w2a);  // (5, 8) pairs
    const f32x2* B1 = reinterpret_cast<const f32x2*>(b2a);
    const f32x2* W2 = reinterpret_cast<const f32x2*>(w2b);  // (16, 8) pairs
    const f32x2* B2 = reinterpret_cast<const f32x2*>(b2b);
    const f32x2* W3 = reinterpret_cast<const f32x2*>(w2c);  // 16 pairs {w0,w1}
    const f32x2  b3 = *reinterpret_cast<const f32x2*>(b2c);

    // Per-row loads. inputs row is 8B-aligned f32x2; Z row is 4B-aligned -> scalar.
    const f32x2 xv = reinterpret_cast<const f32x2*>(inputs)[row];
    const float y = Yin[row];
    float z[LDIM];
    #pragma unroll
    for (int k = 0; k < LDIM; ++k) z[k] = Zin[(size_t)row * LDIM + k];

    // new_Z = Z @ A (5x5 scalar fma)
    float nz[LDIM];
    #pragma unroll
    for (int j = 0; j < LDIM; ++j) nz[j] = 0.0f;
    #pragma unroll
    for (int k = 0; k < LDIM; ++k)
        #pragma unroll
        for (int j = 0; j < LDIM; ++j)
            nz[j] = fmaf(z[k], A[k * LDIM + j], nz[j]);

    // h = relu(nz @ w2a + b2a), j packed
    f32x2 h[HDIM / 2];
    #pragma unroll
    for (int jp = 0; jp < HDIM / 2; ++jp) h[jp] = B1[jp];
    #pragma unroll
    for (int k = 0; k < LDIM; ++k) {
        const f32x2 a2 = {nz[k], nz[k]};
        #pragma unroll
        for (int jp = 0; jp < HDIM / 2; ++jp)
            h[jp] = fma2(a2, W1[k * (HDIM / 2) + jp], h[jp]);
    }
    const f32x2 zero = {0.0f, 0.0f};
    #pragma unroll
    for (int jp = 0; jp < HDIM / 2; ++jp) h[jp] = max2(h[jp], zero);

    // g2 = relu(h @ w2b + b2b), j packed
    f32x2 g2[HDIM / 2];
    #pragma unroll
    for (int jp = 0; jp < HDIM / 2; ++jp) g2[jp] = B2[jp];
    #pragma unroll
    for (int k = 0; k < HDIM; ++k) {
        const float hk = (k & 1) ? h[k >> 1].y : h[k >> 1].x;  // static index
        const f32x2 a2 = {hk, hk};
        #pragma unroll
        for (int jp = 0; jp < HDIM / 2; ++jp)
            g2[jp] = fma2(a2, W2[k * (HDIM / 2) + jp], g2[jp]);
    }
    #pragma unroll
    for (int jp = 0; jp < HDIM / 2; ++jp) g2[jp] = max2(g2[jp], zero);

    // {k1,k2} = g2 @ w2c + b2c, packed pair accumulator
    f32x2 k12 = b3;
    #pragma unroll
    for (int k = 0; k < HDIM; ++k) {
        const float gk = (k & 1) ? g2[k >> 1].y : g2[k >> 1].x;
        const f32x2 a2 = {gk, gk};
        k12 = fma2(a2, W3[k], k12);
    }

    const float K1 = fabsf(k12.x);
    const float K2 = fabsf(k12.y);
    // DY = -Y + k1*x1 - k2*x2 (+ 0*g); new_S = Y + DY (reference op order)
    const float ns = y + (-y + K1 * xv.x - K2 * xv.y);

    // Plain cached stores (R11: NT vs cached was exactly neutral).
    out[row] = ns;
    out[(size_t)6 * B + row] = ns;
    float* oz = out + (size_t)B + (size_t)row * LDIM;
    #pragma unroll
    for (int j = 0; j < LDIM; ++j) oz[j] = nz[j];
}

extern "C" void kernel_launch(void* const* d_in, const int* in_sizes, int n_in,
                              void* d_out, int out_size, void* d_ws, size_t ws_size,
                              hipStream_t stream) {
    const float* inputs = (const float*)d_in[0];
    const float* Zin    = (const float*)d_in[1];
    const float* Yin    = (const float*)d_in[2];
    const float* A      = (const float*)d_in[3];
    const float* w2a    = (const float*)d_in[4];
    const float* b2a    = (const float*)d_in[5];
    const float* w2b    = (const float*)d_in[6];
    const float* b2b    = (const float*)d_in[7];
    const float* w2c    = (const float*)d_in[8];
    const float* b2c    = (const float*)d_in[9];

    const unsigned B = (unsigned)in_sizes[2];  // Y has B elements
    const unsigned grid = (B + BLOCK - 1) / BLOCK;

    lpsc_main<<<grid, BLOCK, 0, stream>>>(inputs, Zin, Yin, A, w2a, b2a,
                                          w2b, b2b, w2c, b2c,
                                          (float*)d_out, B);
}